// Round 1
// baseline (620.605 us; speedup 1.0000x reference)
//
#include <hip/hip_runtime.h>
#include <hip/hip_bf16.h>
#include <cstdint>
#include <cstddef>

// Problem constants: B=128, H=1024, L=256, N=64
typedef __bf16 bf16x8 __attribute__((ext_vector_type(8)));
typedef float  f32x4  __attribute__((ext_vector_type(4)));

__device__ __forceinline__ unsigned short f2bf(float f) {
    unsigned u = __builtin_bit_cast(unsigned, f);
    u += 0x7fffu + ((u >> 16) & 1u);          // RNE
    return (unsigned short)(u >> 16);
}

__device__ __forceinline__ float gelu_tanh(float x) {
    // jax.nn.gelu default (approximate=True)
    float z = 0.7978845608028654f * (x + 0.044715f * x * x * x);
    float e = __expf(2.0f * z);
    float t = 1.0f - 2.0f / (e + 1.0f);       // tanh(z)
    return 0.5f * x * (1.0f + t);
}

// ---------------- K1: S4D kernel k[h][t]  (H blocks x 256 threads) -------------
__global__ void k_kernel(const float* __restrict__ log_dt,
                         const float* __restrict__ arl,
                         const float* __restrict__ aim,
                         const float* __restrict__ cre,
                         const float* __restrict__ cim,
                         float* __restrict__ kout) {
    __shared__ float sRe[64], sIm[64], sCr[64], sCi[64];
    const int h = blockIdx.x;
    const int t = threadIdx.x;
    if (t < 64) {
        float dt  = expf(log_dt[h]);
        float ar  = -expf(arl[h * 64 + t]);
        float ai  = aim[h * 64 + t];
        float dre = ar * dt, dim = ai * dt;
        float er  = expf(dre);
        float s, c;
        sincosf(dim, &s, &c);
        float em1r = er * c - 1.0f, em1i = er * s;   // exp(dtA)-1
        float cr = cre[h * 64 + t], ci = cim[h * 64 + t];
        float pr = cr * em1r - ci * em1i;            // C*(exp(dtA)-1)
        float pi = cr * em1i + ci * em1r;
        float inv = 1.0f / (ar * ar + ai * ai);      // /A = *conj(A)/|A|^2
        sCr[t] = (pr * ar + pi * ai) * inv;
        sCi[t] = (pi * ar - pr * ai) * inv;
        sRe[t] = dre; sIm[t] = dim;
    }
    __syncthreads();
    float acc = 0.0f;
    const float tf = (float)t;
    #pragma unroll 8
    for (int n = 0; n < 64; n++) {
        float er = expf(sRe[n] * tf);
        float s, c;
        sincosf(sIm[n] * tf, &s, &c);
        acc += sCr[n] * er * c - sCi[n] * er * s;    // Re(C_disc * exp(dtA*t))
    }
    kout[h * 256 + t] = 2.0f * acc;
}

// ---------------- K1b: pack W_out (2H x H fp32) -> bf16, GLU-paired rows -------
// packed row p = rt*128 + r : r<64 -> g = rt*64+r (a-half), r>=64 -> g = H + rt*64 + (r-64)
__global__ void pack_w(const float* __restrict__ W, unsigned short* __restrict__ Wp) {
    const int p  = blockIdx.x;                 // 0..2047
    const int rt = p >> 7, r = p & 127;
    const int g  = (r < 64) ? (rt * 64 + r) : (1024 + rt * 64 + (r - 64));
    const int t  = threadIdx.x;                // 0..255
    const float4 v = *(const float4*)(W + (size_t)g * 1024 + t * 4);
    ushort4 o;
    o.x = f2bf(v.x); o.y = f2bf(v.y); o.z = f2bf(v.z); o.w = f2bf(v.w);
    *(ushort4*)(Wp + (size_t)p * 1024 + t * 4) = o;
}

// ---------------- K2: causal conv + skip + gelu -> y_t[b][l][h] bf16 -----------
// grid (H/32, B), 256 threads. LDS: x_t[256][32], k_t[256][32] fp32 (64 KB).
__global__ void conv_kernel(const float* __restrict__ x,
                            const float* __restrict__ kg,
                            const float* __restrict__ D,
                            unsigned short* __restrict__ yt) {
    __shared__ float xt[256 * 32];
    __shared__ float kt[256 * 32];
    const int b     = blockIdx.y;
    const int hbase = blockIdx.x * 32;
    const int tid   = threadIdx.x;

    // fill LDS transposed: [l][h]; lanes 0..31 distinct h -> conflict-free writes
    {
        const int h  = tid & 31;
        const int c0 = tid >> 5;               // 0..7
        #pragma unroll
        for (int t8 = 0; t8 < 8; t8++) {
            int c4 = c0 + t8 * 8;              // float4 chunk 0..63
            float4 xv = *(const float4*)(x + (((size_t)(b * 1024 + hbase + h)) << 8) + c4 * 4);
            float4 kv = *(const float4*)(kg + (((size_t)(hbase + h)) << 8) + c4 * 4);
            int l = c4 * 4;
            xt[(l + 0) * 32 + h] = xv.x; xt[(l + 1) * 32 + h] = xv.y;
            xt[(l + 2) * 32 + h] = xv.z; xt[(l + 3) * 32 + h] = xv.w;
            kt[(l + 0) * 32 + h] = kv.x; kt[(l + 1) * 32 + h] = kv.y;
            kt[(l + 2) * 32 + h] = kv.z; kt[(l + 3) * 32 + h] = kv.w;
        }
    }
    __syncthreads();

    const int h    = tid & 31;                 // channel within group
    const int slot = tid >> 5;                 // 0..7 (half-wave granularity)
    const float Dh = D[hbase + h];
    // balanced chunk sets per slot: sum of trip counts uniform across waves
    int cs[4] = { slot, 15 - slot, 16 + slot, 31 - slot };

    for (int ci = 0; ci < 4; ci++) {
        const int c  = cs[ci];
        const int l0 = c * 8;                  // output chunk [l0, l0+8)
        float acc[8];
        #pragma unroll
        for (int i = 0; i < 8; i++) acc[i] = 0.0f;
        float kw[16];                          // kw[v] = k[base-8+v]
        #pragma unroll
        for (int v = 0; v < 8; v++) kw[8 + v] = kt[(l0 + v) * 32 + h];
        float X[8];
        for (int base = l0; base > 0; base -= 8) {
            #pragma unroll
            for (int v = 0; v < 8; v++) kw[v] = kt[(base - 8 + v) * 32 + h];
            const int jb = l0 - base;
            #pragma unroll
            for (int u = 0; u < 8; u++) X[u] = xt[(jb + u) * 32 + h];
            #pragma unroll
            for (int u = 0; u < 8; u++)
                #pragma unroll
                for (int i = 0; i < 8; i++)
                    acc[i] = fmaf(kw[8 + i - u], X[u], acc[i]);   // k[base+i-u]*x[jb+u]
            #pragma unroll
            for (int v = 0; v < 8; v++) kw[8 + v] = kw[v];
        }
        // final block base==0: k[t<0] = 0 -> triangular
        #pragma unroll
        for (int u = 0; u < 8; u++) X[u] = xt[(l0 + u) * 32 + h];
        #pragma unroll
        for (int u = 0; u < 8; u++)
            #pragma unroll
            for (int i = u; i < 8; i++)
                acc[i] = fmaf(kw[8 + i - u], X[u], acc[i]);
        // skip + gelu + bf16 store (lanes = h contiguous -> coalesced)
        #pragma unroll
        for (int i = 0; i < 8; i++) {
            float y = acc[i] + Dh * X[i];      // X[i] = x[l0+i]
            yt[(((size_t)(b * 256 + l0 + i)) << 10) + hbase + h] = f2bf(gelu_tanh(y));
        }
    }
}

// ---------------- K3: bf16 MFMA GEMM (K=1024) + bias + GLU -> out fp32 ---------
// grid (16 row-tiles, 128 batches), 256 threads = 4 waves, each wave 64(l) x 128(g)
__global__ __launch_bounds__(256, 2)
void gemm_glu(const unsigned short* __restrict__ yt,
              const unsigned short* __restrict__ Wp,
              const float* __restrict__ bo,
              float* __restrict__ out) {
    __shared__ __align__(16) unsigned char smem[24576];
    unsigned char* sA = smem;                  // 256 c x 32 k bf16, [k8][c] 16B chunks
    unsigned char* sB = smem + 16384;          // 128 p x 32 k bf16, [k8][p]
    const int rt  = blockIdx.x;                // 0..15 (64 output h per tile)
    const int b   = blockIdx.y;                // 0..127
    const int tid = threadIdx.x;
    const int w = tid >> 6, lane = tid & 63, m = lane & 15, q4 = lane >> 4;

    f32x4 acc[4][8];
    #pragma unroll
    for (int fr = 0; fr < 4; fr++)
        #pragma unroll
        for (int fc = 0; fc < 8; fc++) acc[fr][fc] = (f32x4){0.f, 0.f, 0.f, 0.f};

    const size_t ybase = ((size_t)b) << 18;            // b*256*1024 (elements)
    const size_t wbase = ((size_t)rt) * 128 * 1024;

    for (int k0 = 0; k0 < 1024; k0 += 32) {
        #pragma unroll
        for (int t8 = 0; t8 < 4; t8++) {               // A: 1024 16B chunks
            int q = t8 * 256 + tid;
            int k8 = q >> 8, c = q & 255;
            const unsigned short* gp = yt + ybase + (size_t)c * 1024 + k0 + k8 * 8;
            __builtin_amdgcn_global_load_lds((const __attribute__((address_space(1))) void*)gp,
                                             (__attribute__((address_space(3))) void*)(sA + q * 16),
                                             16, 0, 0);
        }
        #pragma unroll
        for (int t8 = 0; t8 < 2; t8++) {               // B: 512 16B chunks
            int q = t8 * 256 + tid;
            int k8 = q >> 7, p = q & 127;
            const unsigned short* gp = Wp + wbase + (size_t)p * 1024 + k0 + k8 * 8;
            __builtin_amdgcn_global_load_lds((const __attribute__((address_space(1))) void*)gp,
                                             (__attribute__((address_space(3))) void*)(sB + 16384 - 16384 + q * 16),
                                             16, 0, 0);
        }
        __builtin_amdgcn_s_waitcnt(0x0f70);            // vmcnt(0)
        __syncthreads();

        bf16x8 aF[4];
        #pragma unroll
        for (int fr = 0; fr < 4; fr++)
            aF[fr] = *(const bf16x8*)(sA + ((q4 * 256 + w * 64 + fr * 16 + m) << 4));
        #pragma unroll
        for (int fc = 0; fc < 8; fc++) {
            bf16x8 bF = *(const bf16x8*)(sB + ((q4 * 128 + fc * 16 + m) << 4));
            #pragma unroll
            for (int fr = 0; fr < 4; fr++)
                acc[fr][fc] = __builtin_amdgcn_mfma_f32_16x16x32_bf16(aF[fr], bF, acc[fr][fc], 0, 0, 0);
        }
        __syncthreads();
    }

    // epilogue: val = (a + b_a) * sigmoid(gate + b_g); direct stores
    const size_t orow = ((size_t)(b * 1024 + rt * 64)) << 8;   // *256
    const int cbase = w * 64;
    #pragma unroll
    for (int fc = 0; fc < 4; fc++) {
        float boa = bo[rt * 64 + fc * 16 + m];
        float bog = bo[1024 + rt * 64 + fc * 16 + m];
        #pragma unroll
        for (int fr = 0; fr < 4; fr++) {
            #pragma unroll
            for (int rg = 0; rg < 4; rg++) {
                float av = acc[fr][fc][rg] + boa;
                float gv = acc[fr][fc + 4][rg] + bog;
                float val = av / (1.0f + __expf(-gv));
                out[orow + (((size_t)(fc * 16 + m)) << 8) + cbase + fr * 16 + q4 * 4 + rg] = val;
            }
        }
    }
}

extern "C" void kernel_launch(void* const* d_in, const int* in_sizes, int n_in,
                              void* d_out, int out_size, void* d_ws, size_t ws_size,
                              hipStream_t stream) {
    const float* x   = (const float*)d_in[0];
    const float* ldt = (const float*)d_in[1];
    const float* arl = (const float*)d_in[2];
    const float* aim = (const float*)d_in[3];
    const float* cre = (const float*)d_in[4];
    const float* cim = (const float*)d_in[5];
    const float* D   = (const float*)d_in[6];
    const float* Wo  = (const float*)d_in[7];
    const float* bo  = (const float*)d_in[8];
    float* out = (float*)d_out;

    const size_t kOff = 0;                         // H*L fp32     = 1 MB
    const size_t wOff = (size_t)1 << 20;           // 2H*H bf16    = 4 MB
    const size_t yOff = wOff + ((size_t)1 << 22);  // B*L*H bf16   = 64 MB
    const size_t need = yOff + (size_t)128 * 256 * 1024 * 2;
    if (ws_size < need) return;                    // loud failure, no corruption

    float*          kg = (float*)((char*)d_ws + kOff);
    unsigned short* Wp = (unsigned short*)((char*)d_ws + wOff);
    unsigned short* yt = (unsigned short*)((char*)d_ws + yOff);

    k_kernel  <<<1024, 256, 0, stream>>>(ldt, arl, aim, cre, cim, kg);
    pack_w    <<<2048, 256, 0, stream>>>(Wo, Wp);
    conv_kernel<<<dim3(32, 128), 256, 0, stream>>>(x, kg, D, yt);
    gemm_glu  <<<dim3(16, 128), 256, 0, stream>>>(yt, Wp, bo, out);
}